// Round 5
// baseline (2473.298 us; speedup 1.0000x reference)
//
#include <hip/hip_runtime.h>

#define B 8
#define N 16384
#define NPOINT 1024
#define NSAMPLE 32
#define CDIM 128

// d_out layout (floats), reference return order:
// new_xyz [B,NPOINT,3], new_points [B,NPOINT,NSAMPLE,CDIM], idx [B,NPOINT,NSAMPLE], grouped_xyz [B,NPOINT,NSAMPLE,3]
#define OFF_NEWXYZ 0
#define OFF_NEWPTS (B * NPOINT * 3)                           // 24576
#define OFF_IDX    (OFF_NEWPTS + B * NPOINT * NSAMPLE * CDIM) // 33579008
#define OFF_GXYZ   (OFF_IDX + B * NPOINT * NSAMPLE)           // 33841152

// ---------------- FPS: one block (1024 threads) per batch ----------------
// Exact f32 left-assoc ops (no FMA contraction); argmax first-index tie-break.
// px/py/pz are made OPAQUE via inline asm after the initial load so the
// compiler cannot rematerialize the global loads inside the step loop
// (round-4 evidence: VGPR=48 -> coords were re-streamed from L2 every step).
// One barrier per step: every wave redundantly reduces the per-wave results
// from double-buffered LDS, then issues its own uniform s_load of the winning
// centroid.
__global__ __launch_bounds__(1024, 4) void fps_kernel(const float* __restrict__ xyz,
                                                      float* out) {
    const int b = blockIdx.x;
    const int t = threadIdx.x;
    const float* xb = xyz + (size_t)b * N * 3;

    float px[16], py[16], pz[16], d[16];
#pragma unroll
    for (int k = 0; k < 16; ++k) {
        const int n = k * 1024 + t;
        px[k] = xb[n * 3 + 0];
        py[k] = xb[n * 3 + 1];
        pz[k] = xb[n * 3 + 2];
        d[k] = 1e10f;
        // anti-rematerialization fence: value now originates from the asm,
        // not from a reloadable global load -> must stay in a VGPR.
        asm volatile("" : "+v"(px[k]), "+v"(py[k]), "+v"(pz[k]));
    }

    __shared__ float wv[2][16];
    __shared__ int   wn[2][16];

    float* nxo = out + OFF_NEWXYZ + (size_t)b * NPOINT * 3;
    const int wid = t >> 6;
    const int lane = t & 63;
    int far = 0;

    for (int s = 0; s < NPOINT; ++s) {
        // uniform scalar broadcast load of the centroid (SGPR address -> s_load)
        const int fs = __builtin_amdgcn_readfirstlane(far);
        const float* cp = xb + fs * 3;
        const float cx = cp[0];
        const float cy = cp[1];
        const float cz = cp[2];
        if (t == 0) {
            nxo[s * 3 + 0] = cx;
            nxo[s * 3 + 1] = cy;
            nxo[s * 3 + 2] = cz;
        }
        if (s == NPOINT - 1) break;                  // last argmax is discarded

        float best = -1.0f;
        int bk = 0;                                  // 0..15, inline-const cndmask
#pragma unroll
        for (int k = 0; k < 16; ++k) {
            const float dx = __fsub_rn(px[k], cx);
            const float dy = __fsub_rn(py[k], cy);
            const float dz = __fsub_rn(pz[k], cz);
            const float dist = __fadd_rn(__fadd_rn(__fmul_rn(dx, dx), __fmul_rn(dy, dy)),
                                         __fmul_rn(dz, dz));
            const float dk = fminf(d[k], dist);
            d[k] = dk;
            if (dk > best) { best = dk; bk = k; }    // ascending n: first max kept
        }
        int bn = bk * 1024 + t;
        // wave (64-lane) argmax butterfly, tie -> smaller index
#pragma unroll
        for (int off = 32; off >= 1; off >>= 1) {
            const float ov = __shfl_xor(best, off);
            const int   on = __shfl_xor(bn, off);
            if (ov > best || (ov == best && on < bn)) { best = ov; bn = on; }
        }
        if (lane == 0) { wv[s & 1][wid] = best; wn[s & 1][wid] = bn; }
        __syncthreads();
        // every wave redundantly reduces the 16 per-wave winners
        float v  = (lane < 16) ? wv[s & 1][lane] : -1.0f;
        int   n2 = (lane < 16) ? wn[s & 1][lane] : 0x7fffffff;
#pragma unroll
        for (int off = 8; off >= 1; off >>= 1) {
            const float ov = __shfl_xor(v, off);
            const int   on = __shfl_xor(n2, off);
            if (ov > v || (ov == v && on < n2)) { v = ov; n2 = on; }
        }
        far = __shfl(n2, 0);
    }
}

// ---------------- Ball query: one 64-lane wave per centroid ----------------
// Selects the 32 smallest indices n with d2 < r^2 where
// d2 = (|s|^2 + |x|^2) - 2*(s.x)  (left-assoc f32, matching the reference).
// Fill short groups with the first valid index. Writes idx (as float) and grouped_xyz.
__global__ __launch_bounds__(256) void ballq_kernel(const float* __restrict__ xyz,
                                                    const float* __restrict__ radius_p,
                                                    float* out) {
    const int wib = threadIdx.x >> 6;
    const int lane = threadIdx.x & 63;
    const int gw = blockIdx.x * 4 + wib;   // 0..8191
    const int b = gw >> 10;
    const int s = gw & 1023;

    const float r = radius_p[0];
    const float r2 = __fmul_rn(r, r);

    const float* xb = xyz + (size_t)b * N * 3;
    const float* nx = out + OFF_NEWXYZ + (size_t)(b * NPOINT + s) * 3;
    const float c0 = nx[0], c1 = nx[1], c2 = nx[2];
    const float ss_s = __fadd_rn(__fadd_rn(__fmul_rn(c0, c0), __fmul_rn(c1, c1)),
                                 __fmul_rn(c2, c2));

    float* oidx = out + OFF_IDX + (size_t)(b * NPOINT + s) * NSAMPLE;
    float* ogx  = out + OFF_GXYZ + (size_t)(b * NPOINT + s) * NSAMPLE * 3;

    int filled = 0;
    int first = -1;
    for (int n0 = 0; n0 < N; n0 += 64) {
        const int n = n0 + lane;
        const float x = xb[n * 3 + 0];
        const float y = xb[n * 3 + 1];
        const float z = xb[n * 3 + 2];
        const float ssx = __fadd_rn(__fadd_rn(__fmul_rn(x, x), __fmul_rn(y, y)),
                                    __fmul_rn(z, z));
        const float dot = __fadd_rn(__fadd_rn(__fmul_rn(c0, x), __fmul_rn(c1, y)),
                                    __fmul_rn(c2, z));
        const float d2 = __fsub_rn(__fadd_rn(ss_s, ssx), __fmul_rn(2.0f, dot));
        const bool in = d2 < r2;
        const unsigned long long m = __ballot(in);
        if (first < 0 && m != 0ull) first = n0 + (int)__builtin_ctzll(m);
        if (in) {
            const int pos = filled + (int)__popcll(m & ((1ull << lane) - 1ull));
            if (pos < NSAMPLE) {
                oidx[pos] = (float)n;
                ogx[pos * 3 + 0] = __fsub_rn(x, c0);
                ogx[pos * 3 + 1] = __fsub_rn(y, c1);
                ogx[pos * 3 + 2] = __fsub_rn(z, c2);
            }
        }
        filled += (int)__popcll(m);
        if (filled >= NSAMPLE) break;
    }
    if (filled < NSAMPLE) {
        if (first < 0) first = 0;  // cannot happen (centroid is in its own ball), safety
        const float fx = xb[first * 3 + 0];
        const float fy = xb[first * 3 + 1];
        const float fz = xb[first * 3 + 2];
        const float g0 = __fsub_rn(fx, c0);
        const float g1 = __fsub_rn(fy, c1);
        const float g2 = __fsub_rn(fz, c2);
        for (int pos = filled + lane; pos < NSAMPLE; pos += 64) {
            oidx[pos] = (float)first;
            ogx[pos * 3 + 0] = g0;
            ogx[pos * 3 + 1] = g1;
            ogx[pos * 3 + 2] = g2;
        }
    }
}

// ---------------- new_points gather: one block per (b,s) ----------------
__global__ __launch_bounds__(256) void gather_kernel(const float* __restrict__ points,
                                                     float* out) {
    const int blk = blockIdx.x;            // b*NPOINT + s
    const int w = threadIdx.x >> 6;
    const int lane = threadIdx.x & 63;
    const int b = blk >> 10;

    const float* oidx = out + OFF_IDX + (size_t)blk * NSAMPLE;
    const float* pb = points + (size_t)b * N * CDIM;
    float* onp = out + OFF_NEWPTS + (size_t)blk * NSAMPLE * CDIM;

#pragma unroll
    for (int i = 0; i < 8; ++i) {
        const int slot = w * 8 + i;
        const int n = (int)oidx[slot];
        const float2 v = *(const float2*)(pb + (size_t)n * CDIM + lane * 2);
        *(float2*)(onp + (size_t)slot * CDIM + lane * 2) = v;
    }
}

extern "C" void kernel_launch(void* const* d_in, const int* in_sizes, int n_in,
                              void* d_out, int out_size, void* d_ws, size_t ws_size,
                              hipStream_t stream) {
    // inputs: [0]=npoint(int,1), [1]=radius(f32,1), [2]=xyz(f32, B*N*3), [3]=points(f32, B*N*CDIM)
    const float* xyz = (const float*)d_in[2];
    const float* points = (const float*)d_in[3];
    const float* radius = (const float*)d_in[1];
    float* out = (float*)d_out;

    hipLaunchKernelGGL(fps_kernel, dim3(B), dim3(1024), 0, stream, xyz, out);
    hipLaunchKernelGGL(ballq_kernel, dim3((B * NPOINT) / 4), dim3(256), 0, stream, xyz, radius, out);
    hipLaunchKernelGGL(gather_kernel, dim3(B * NPOINT), dim3(256), 0, stream, points, out);
}

// Round 8
// 2439.217 us; speedup vs baseline: 1.0140x; 1.0140x over previous
//
#include <hip/hip_runtime.h>

#define B 8
#define N 16384
#define NPOINT 1024
#define NSAMPLE 32
#define CDIM 128

// d_out layout (floats), reference return order:
// new_xyz [B,NPOINT,3], new_points [B,NPOINT,NSAMPLE,CDIM], idx [B,NPOINT,NSAMPLE], grouped_xyz [B,NPOINT,NSAMPLE,3]
#define OFF_NEWXYZ 0
#define OFF_NEWPTS (B * NPOINT * 3)                           // 24576
#define OFF_IDX    (OFF_NEWPTS + B * NPOINT * NSAMPLE * CDIM) // 33579008
#define OFF_GXYZ   (OFF_IDX + B * NPOINT * NSAMPLE)           // 33841152

// ---------------- FPS: one block (1024 threads) per batch ----------------
// Exact f32 left-assoc ops (no FMA contraction); argmax first-index tie-break.
// Rounds 4/5 showed the register allocator refuses to keep 48 coord floats
// resident (VGPR=48, scratch re-stream ~2.3 µs/step). Explicit placement:
// x,y live in LDS (16384*8B = 128 KB), z in 16 statically-indexed VGPRs.
// k-loop = 16x ds_read_b64 + pure VALU; DS and VALU pipes overlap.
__global__ __launch_bounds__(1024) void fps_kernel(const float* __restrict__ xyz,
                                                   float* out) {
    const int b = blockIdx.x;
    const int t = threadIdx.x;
    const float* xb = xyz + (size_t)b * N * 3;

    __shared__ float sxy[N * 2];       // x at [2n], y at [2n+1] — 128 KiB
    __shared__ float wv[2][16];
    __shared__ int   wn[2][16];

    float pz[16], d[16];
#pragma unroll
    for (int k = 0; k < 16; ++k) {
        const int n = k * 1024 + t;
        sxy[n * 2 + 0] = xb[n * 3 + 0];
        sxy[n * 2 + 1] = xb[n * 3 + 1];
        pz[k] = xb[n * 3 + 2];
        d[k] = 1e10f;
    }
    __syncthreads();

    float* nxo = out + OFF_NEWXYZ + (size_t)b * NPOINT * 3;
    const int wid = t >> 6;
    const int lane = t & 63;
    int far = 0;

    for (int s = 0; s < NPOINT; ++s) {
        // uniform scalar broadcast load of the centroid (SGPR address -> s_load)
        const int fs = __builtin_amdgcn_readfirstlane(far);
        const float* cp = xb + fs * 3;
        const float cx = cp[0];
        const float cy = cp[1];
        const float cz = cp[2];
        if (t == 0) {
            nxo[s * 3 + 0] = cx;
            nxo[s * 3 + 1] = cy;
            nxo[s * 3 + 2] = cz;
        }
        if (s == NPOINT - 1) break;                  // last argmax is discarded

        float best = -1.0f;
        int bk = 0;                                  // 0..15, inline-const cndmask
#pragma unroll
        for (int k = 0; k < 16; ++k) {
            const int n = k * 1024 + t;
            const float2 xy = *(const float2*)(&sxy[n * 2]);   // ds_read_b64
            const float dx = __fsub_rn(xy.x, cx);
            const float dy = __fsub_rn(xy.y, cy);
            const float dz = __fsub_rn(pz[k], cz);
            const float dist = __fadd_rn(__fadd_rn(__fmul_rn(dx, dx), __fmul_rn(dy, dy)),
                                         __fmul_rn(dz, dz));
            const float dk = fminf(d[k], dist);
            d[k] = dk;
            if (dk > best) { best = dk; bk = k; }    // ascending n: first max kept
        }
        int bn = bk * 1024 + t;
        // wave (64-lane) argmax butterfly, tie -> smaller index
#pragma unroll
        for (int off = 32; off >= 1; off >>= 1) {
            const float ov = __shfl_xor(best, off);
            const int   on = __shfl_xor(bn, off);
            if (ov > best || (ov == best && on < bn)) { best = ov; bn = on; }
        }
        if (lane == 0) { wv[s & 1][wid] = best; wn[s & 1][wid] = bn; }
        __syncthreads();
        // every wave redundantly reduces the 16 per-wave winners (1 barrier/step;
        // parity double-buffer makes the cross-step write-after-read safe)
        float v  = (lane < 16) ? wv[s & 1][lane] : -1.0f;
        int   n2 = (lane < 16) ? wn[s & 1][lane] : 0x7fffffff;
#pragma unroll
        for (int off = 8; off >= 1; off >>= 1) {
            const float ov = __shfl_xor(v, off);
            const int   on = __shfl_xor(n2, off);
            if (ov > v || (ov == v && on < n2)) { v = ov; n2 = on; }
        }
        far = __shfl(n2, 0);
    }
}

// ---------------- Ball query: one 64-lane wave per centroid ----------------
// Selects the 32 smallest indices n with d2 < r^2 where
// d2 = (|s|^2 + |x|^2) - 2*(s.x)  (left-assoc f32, matching the reference).
// Fill short groups with the first valid index. Writes idx (as float) and grouped_xyz.
__global__ __launch_bounds__(256) void ballq_kernel(const float* __restrict__ xyz,
                                                    const float* __restrict__ radius_p,
                                                    float* out) {
    const int wib = threadIdx.x >> 6;
    const int lane = threadIdx.x & 63;
    const int gw = blockIdx.x * 4 + wib;   // 0..8191
    const int b = gw >> 10;
    const int s = gw & 1023;

    const float r = radius_p[0];
    const float r2 = __fmul_rn(r, r);

    const float* xb = xyz + (size_t)b * N * 3;
    const float* nx = out + OFF_NEWXYZ + (size_t)(b * NPOINT + s) * 3;
    const float c0 = nx[0], c1 = nx[1], c2 = nx[2];
    const float ss_s = __fadd_rn(__fadd_rn(__fmul_rn(c0, c0), __fmul_rn(c1, c1)),
                                 __fmul_rn(c2, c2));

    float* oidx = out + OFF_IDX + (size_t)(b * NPOINT + s) * NSAMPLE;
    float* ogx  = out + OFF_GXYZ + (size_t)(b * NPOINT + s) * NSAMPLE * 3;

    int filled = 0;
    int first = -1;
    for (int n0 = 0; n0 < N; n0 += 64) {
        const int n = n0 + lane;
        const float x = xb[n * 3 + 0];
        const float y = xb[n * 3 + 1];
        const float z = xb[n * 3 + 2];
        const float ssx = __fadd_rn(__fadd_rn(__fmul_rn(x, x), __fmul_rn(y, y)),
                                    __fmul_rn(z, z));
        const float dot = __fadd_rn(__fadd_rn(__fmul_rn(c0, x), __fmul_rn(c1, y)),
                                    __fmul_rn(c2, z));
        const float d2 = __fsub_rn(__fadd_rn(ss_s, ssx), __fmul_rn(2.0f, dot));
        const bool in = d2 < r2;
        const unsigned long long m = __ballot(in);
        if (first < 0 && m != 0ull) first = n0 + (int)__builtin_ctzll(m);
        if (in) {
            const int pos = filled + (int)__popcll(m & ((1ull << lane) - 1ull));
            if (pos < NSAMPLE) {
                oidx[pos] = (float)n;
                ogx[pos * 3 + 0] = __fsub_rn(x, c0);
                ogx[pos * 3 + 1] = __fsub_rn(y, c1);
                ogx[pos * 3 + 2] = __fsub_rn(z, c2);
            }
        }
        filled += (int)__popcll(m);
        if (filled >= NSAMPLE) break;
    }
    if (filled < NSAMPLE) {
        if (first < 0) first = 0;  // cannot happen (centroid is in its own ball), safety
        const float fx = xb[first * 3 + 0];
        const float fy = xb[first * 3 + 1];
        const float fz = xb[first * 3 + 2];
        const float g0 = __fsub_rn(fx, c0);
        const float g1 = __fsub_rn(fy, c1);
        const float g2 = __fsub_rn(fz, c2);
        for (int pos = filled + lane; pos < NSAMPLE; pos += 64) {
            oidx[pos] = (float)first;
            ogx[pos * 3 + 0] = g0;
            ogx[pos * 3 + 1] = g1;
            ogx[pos * 3 + 2] = g2;
        }
    }
}

// ---------------- new_points gather: one block per (b,s) ----------------
__global__ __launch_bounds__(256) void gather_kernel(const float* __restrict__ points,
                                                     float* out) {
    const int blk = blockIdx.x;            // b*NPOINT + s
    const int w = threadIdx.x >> 6;
    const int lane = threadIdx.x & 63;
    const int b = blk >> 10;

    const float* oidx = out + OFF_IDX + (size_t)blk * NSAMPLE;
    const float* pb = points + (size_t)b * N * CDIM;
    float* onp = out + OFF_NEWPTS + (size_t)blk * NSAMPLE * CDIM;

#pragma unroll
    for (int i = 0; i < 8; ++i) {
        const int slot = w * 8 + i;
        const int n = (int)oidx[slot];
        const float2 v = *(const float2*)(pb + (size_t)n * CDIM + lane * 2);
        *(float2*)(onp + (size_t)slot * CDIM + lane * 2) = v;
    }
}

extern "C" void kernel_launch(void* const* d_in, const int* in_sizes, int n_in,
                              void* d_out, int out_size, void* d_ws, size_t ws_size,
                              hipStream_t stream) {
    // inputs: [0]=npoint(int,1), [1]=radius(f32,1), [2]=xyz(f32, B*N*3), [3]=points(f32, B*N*CDIM)
    const float* xyz = (const float*)d_in[2];
    const float* points = (const float*)d_in[3];
    const float* radius = (const float*)d_in[1];
    float* out = (float*)d_out;

    hipLaunchKernelGGL(fps_kernel, dim3(B), dim3(1024), 0, stream, xyz, out);
    hipLaunchKernelGGL(ballq_kernel, dim3((B * NPOINT) / 4), dim3(256), 0, stream, xyz, radius, out);
    hipLaunchKernelGGL(gather_kernel, dim3(B * NPOINT), dim3(256), 0, stream, points, out);
}

// Round 9
// 2041.389 us; speedup vs baseline: 1.2116x; 1.1949x over previous
//
#include <hip/hip_runtime.h>

#define B 8
#define N 16384
#define NPOINT 1024
#define NSAMPLE 32
#define CDIM 128

// d_out layout (floats), reference return order:
// new_xyz [B,NPOINT,3], new_points [B,NPOINT,NSAMPLE,CDIM], idx [B,NPOINT,NSAMPLE], grouped_xyz [B,NPOINT,NSAMPLE,3]
#define OFF_NEWXYZ 0
#define OFF_NEWPTS (B * NPOINT * 3)                           // 24576
#define OFF_IDX    (OFF_NEWPTS + B * NPOINT * NSAMPLE * CDIM) // 33579008
#define OFF_GXYZ   (OFF_IDX + B * NPOINT * NSAMPLE)           // 33841152

// ---------------- FPS: one block (1024 threads) per batch ----------------
// Exact f32 left-assoc ops (no FMA contraction); argmax first-index tie-break.
// x,y in LDS (128 KiB), z + d in statically-indexed VGPRs (rule #20).
// Argmax reduce uses u64-packed keys: key = (~bits(d) << 14) | n. For d >= 0,
// ~bits(d) is monotone-DEcreasing in d, so u64-min == (max d, tie -> min n) —
// bit-exactly the reference argmax. One barrier/step; wave keys go through a
// parity-double-buffered LDS array (write->barrier->read spans a barrier; the
// next write to the same parity slot is two steps away, separated by another
// barrier -> race-free).
__global__ __launch_bounds__(1024) void fps_kernel(const float* __restrict__ xyz,
                                                   float* out) {
    const int b = blockIdx.x;
    const int t = threadIdx.x;
    const float* xb = xyz + (size_t)b * N * 3;

    __shared__ float sxy[N * 2];                 // x at [2n], y at [2n+1] — 128 KiB
    __shared__ unsigned long long wkey[2][16];   // per-wave packed winners

    float pz[16], d[16];
#pragma unroll
    for (int k = 0; k < 16; ++k) {
        const int n = k * 1024 + t;
        sxy[n * 2 + 0] = xb[n * 3 + 0];
        sxy[n * 2 + 1] = xb[n * 3 + 1];
        pz[k] = xb[n * 3 + 2];
        d[k] = 1e10f;
    }
    __syncthreads();

    float* nxo = out + OFF_NEWXYZ + (size_t)b * NPOINT * 3;
    const int wid = t >> 6;
    const int lane = t & 63;
    int far = 0;

    for (int s = 0; s < NPOINT; ++s) {
        // uniform scalar broadcast load of the centroid (SGPR address -> s_load)
        const int fs = __builtin_amdgcn_readfirstlane(far);
        const float* cp = xb + fs * 3;
        const float cx = cp[0];
        const float cy = cp[1];
        const float cz = cp[2];
        if (t == 0) {
            nxo[s * 3 + 0] = cx;
            nxo[s * 3 + 1] = cy;
            nxo[s * 3 + 2] = cz;
        }
        if (s == NPOINT - 1) break;                  // last argmax is discarded

        float best = -1.0f;
        int bk = 0;                                  // 0..15, inline-const cndmask
#pragma unroll
        for (int k = 0; k < 16; ++k) {
            const int n = k * 1024 + t;
            const float2 xy = *(const float2*)(&sxy[n * 2]);   // ds_read_b64
            const float dx = __fsub_rn(xy.x, cx);
            const float dy = __fsub_rn(xy.y, cy);
            const float dz = __fsub_rn(pz[k], cz);
            const float dist = __fadd_rn(__fadd_rn(__fmul_rn(dx, dx), __fmul_rn(dy, dy)),
                                         __fmul_rn(dz, dz));
            const float dk = fminf(d[k], dist);
            d[k] = dk;
            if (dk > best) { best = dk; bk = k; }    // ascending n: first max kept
        }
        // pack: d >= 0 always (d = min of squared distances after step 0's 1e10
        // is replaced; best >= d[0] >= 0), so ~bits is monotone decreasing.
        unsigned long long key =
            (((unsigned long long)(~__float_as_uint(best))) << 14) |
            (unsigned long long)(unsigned)(bk * 1024 + t);
        // wave (64-lane) u64-min butterfly: 1 cmp_u64 + 2 cndmask per level
#pragma unroll
        for (int off = 32; off >= 1; off >>= 1) {
            const unsigned long long o = __shfl_xor(key, off);
            if (o < key) key = o;
        }
        if (lane == 0) wkey[s & 1][wid] = key;
        __syncthreads();
        // all 64 lanes broadcast-read the 16 wave keys (same addr per 16-lane
        // group = LDS broadcast), 4-level butterfly -> every lane holds winner
        unsigned long long k2 = wkey[s & 1][lane & 15];
#pragma unroll
        for (int off = 8; off >= 1; off >>= 1) {
            const unsigned long long o = __shfl_xor(k2, off);
            if (o < k2) k2 = o;
        }
        far = (int)(k2 & 16383ull);
    }
}

// ---------------- Ball query: one 64-lane wave per centroid ----------------
// Selects the 32 smallest indices n with d2 < r^2 where
// d2 = (|s|^2 + |x|^2) - 2*(s.x)  (left-assoc f32, matching the reference).
// Fill short groups with the first valid index. Writes idx (as float) and grouped_xyz.
__global__ __launch_bounds__(256) void ballq_kernel(const float* __restrict__ xyz,
                                                    const float* __restrict__ radius_p,
                                                    float* out) {
    const int wib = threadIdx.x >> 6;
    const int lane = threadIdx.x & 63;
    const int gw = blockIdx.x * 4 + wib;   // 0..8191
    const int b = gw >> 10;
    const int s = gw & 1023;

    const float r = radius_p[0];
    const float r2 = __fmul_rn(r, r);

    const float* xb = xyz + (size_t)b * N * 3;
    const float* nx = out + OFF_NEWXYZ + (size_t)(b * NPOINT + s) * 3;
    const float c0 = nx[0], c1 = nx[1], c2 = nx[2];
    const float ss_s = __fadd_rn(__fadd_rn(__fmul_rn(c0, c0), __fmul_rn(c1, c1)),
                                 __fmul_rn(c2, c2));

    float* oidx = out + OFF_IDX + (size_t)(b * NPOINT + s) * NSAMPLE;
    float* ogx  = out + OFF_GXYZ + (size_t)(b * NPOINT + s) * NSAMPLE * 3;

    int filled = 0;
    int first = -1;
    for (int n0 = 0; n0 < N; n0 += 64) {
        const int n = n0 + lane;
        const float x = xb[n * 3 + 0];
        const float y = xb[n * 3 + 1];
        const float z = xb[n * 3 + 2];
        const float ssx = __fadd_rn(__fadd_rn(__fmul_rn(x, x), __fmul_rn(y, y)),
                                    __fmul_rn(z, z));
        const float dot = __fadd_rn(__fadd_rn(__fmul_rn(c0, x), __fmul_rn(c1, y)),
                                    __fmul_rn(c2, z));
        const float d2 = __fsub_rn(__fadd_rn(ss_s, ssx), __fmul_rn(2.0f, dot));
        const bool in = d2 < r2;
        const unsigned long long m = __ballot(in);
        if (first < 0 && m != 0ull) first = n0 + (int)__builtin_ctzll(m);
        if (in) {
            const int pos = filled + (int)__popcll(m & ((1ull << lane) - 1ull));
            if (pos < NSAMPLE) {
                oidx[pos] = (float)n;
                ogx[pos * 3 + 0] = __fsub_rn(x, c0);
                ogx[pos * 3 + 1] = __fsub_rn(y, c1);
                ogx[pos * 3 + 2] = __fsub_rn(z, c2);
            }
        }
        filled += (int)__popcll(m);
        if (filled >= NSAMPLE) break;
    }
    if (filled < NSAMPLE) {
        if (first < 0) first = 0;  // cannot happen (centroid is in its own ball), safety
        const float fx = xb[first * 3 + 0];
        const float fy = xb[first * 3 + 1];
        const float fz = xb[first * 3 + 2];
        const float g0 = __fsub_rn(fx, c0);
        const float g1 = __fsub_rn(fy, c1);
        const float g2 = __fsub_rn(fz, c2);
        for (int pos = filled + lane; pos < NSAMPLE; pos += 64) {
            oidx[pos] = (float)first;
            ogx[pos * 3 + 0] = g0;
            ogx[pos * 3 + 1] = g1;
            ogx[pos * 3 + 2] = g2;
        }
    }
}

// ---------------- new_points gather: one block per (b,s) ----------------
__global__ __launch_bounds__(256) void gather_kernel(const float* __restrict__ points,
                                                     float* out) {
    const int blk = blockIdx.x;            // b*NPOINT + s
    const int w = threadIdx.x >> 6;
    const int lane = threadIdx.x & 63;
    const int b = blk >> 10;

    const float* oidx = out + OFF_IDX + (size_t)blk * NSAMPLE;
    const float* pb = points + (size_t)b * N * CDIM;
    float* onp = out + OFF_NEWPTS + (size_t)blk * NSAMPLE * CDIM;

#pragma unroll
    for (int i = 0; i < 8; ++i) {
        const int slot = w * 8 + i;
        const int n = (int)oidx[slot];
        const float2 v = *(const float2*)(pb + (size_t)n * CDIM + lane * 2);
        *(float2*)(onp + (size_t)slot * CDIM + lane * 2) = v;
    }
}

extern "C" void kernel_launch(void* const* d_in, const int* in_sizes, int n_in,
                              void* d_out, int out_size, void* d_ws, size_t ws_size,
                              hipStream_t stream) {
    // inputs: [0]=npoint(int,1), [1]=radius(f32,1), [2]=xyz(f32, B*N*3), [3]=points(f32, B*N*CDIM)
    const float* xyz = (const float*)d_in[2];
    const float* points = (const float*)d_in[3];
    const float* radius = (const float*)d_in[1];
    float* out = (float*)d_out;

    hipLaunchKernelGGL(fps_kernel, dim3(B), dim3(1024), 0, stream, xyz, out);
    hipLaunchKernelGGL(ballq_kernel, dim3((B * NPOINT) / 4), dim3(256), 0, stream, xyz, radius, out);
    hipLaunchKernelGGL(gather_kernel, dim3(B * NPOINT), dim3(256), 0, stream, points, out);
}

// Round 10
// 1978.883 us; speedup vs baseline: 1.2498x; 1.0316x over previous
//
#include <hip/hip_runtime.h>

#define B 8
#define N 16384
#define NPOINT 1024
#define NSAMPLE 32
#define CDIM 128

// d_out layout (floats), reference return order:
// new_xyz [B,NPOINT,3], new_points [B,NPOINT,NSAMPLE,CDIM], idx [B,NPOINT,NSAMPLE], grouped_xyz [B,NPOINT,NSAMPLE,3]
#define OFF_NEWXYZ 0
#define OFF_NEWPTS (B * NPOINT * 3)                           // 24576
#define OFF_IDX    (OFF_NEWPTS + B * NPOINT * NSAMPLE * CDIM) // 33579008
#define OFF_GXYZ   (OFF_IDX + B * NPOINT * NSAMPLE)           // 33841152

typedef float f32x2 __attribute__((ext_vector_type(2)));

// ---------------- FPS: one block (1024 threads) per batch ----------------
// Exact f32 left-assoc ops; fp-contract OFF so (dx^2+dy^2)+dz^2 keeps its
// rounding. Thread t owns points [16t,16t+16) so index order == (lane,k)
// lex order: wave argmax = f32 max butterfly + ballot + ctz (first-index
// tie-break exact). LDS slots are TRANSPOSED (point n=16t+k at slot
// k*1024+t) so the per-step ds_read pattern stays the conflict-free
// stride-8B one. Distance math on f32x2 vectors -> v_pk_*_f32 (2 pts/instr,
// identical per-half IEEE results). Argmax deferred: d-update is a pure
// min; best = exact-associative max tree; index recovered afterward.
__global__ __launch_bounds__(1024) void fps_kernel(const float* __restrict__ xyz,
                                                   float* out) {
#pragma clang fp contract(off)
    const int b = blockIdx.x;
    const int t = threadIdx.x;
    const float* xb = xyz + (size_t)b * N * 3;

    __shared__ float sxy[N * 2];                 // (x,y) pairs, transposed slots — 128 KiB
    __shared__ unsigned long long wkey[2][16];   // per-wave packed winners (parity dbuf)

    f32x2 pzp[8], dd[8];
#pragma unroll
    for (int k = 0; k < 16; ++k) {
        const int n = t * 16 + k;            // thread-contiguous point ownership
        const int slot = k * 1024 + t;       // transposed LDS slot
        sxy[slot * 2 + 0] = xb[n * 3 + 0];
        sxy[slot * 2 + 1] = xb[n * 3 + 1];
        pzp[k >> 1][k & 1] = xb[n * 3 + 2];
        dd[k >> 1][k & 1] = 1e10f;
    }
    __syncthreads();

    float* nxo = out + OFF_NEWXYZ + (size_t)b * NPOINT * 3;
    const int wid = t >> 6;
    const int lane = t & 63;
    int far = 0;

    for (int s = 0; s < NPOINT; ++s) {
        // centroid: (x,y) via uniform LDS broadcast read; z via uniform s_load.
        const int fs = __builtin_amdgcn_readfirstlane(far);
        const int fslot = (fs & 15) * 1024 + (fs >> 4);
        const f32x2 cl = *(const f32x2*)(&sxy[fslot * 2]);
        const float cz = xb[fs * 3 + 2];
        const float cx = cl.x, cy = cl.y;
        if (t == 0) {
            nxo[s * 3 + 0] = cx;
            nxo[s * 3 + 1] = cy;
            nxo[s * 3 + 2] = cz;
        }
        if (s == NPOINT - 1) break;                  // last argmax is discarded

        const f32x2 cxy = {cx, cy};
        const f32x2 czz = {cz, cz};
#pragma unroll
        for (int j = 0; j < 8; ++j) {                // 2 points per iter, packed
            const int slot0 = (2 * j) * 1024 + t;
            const int slot1 = (2 * j + 1) * 1024 + t;
            const f32x2 xy0 = *(const f32x2*)(&sxy[slot0 * 2]);  // ds_read_b64
            const f32x2 xy1 = *(const f32x2*)(&sxy[slot1 * 2]);
            const f32x2 e0 = xy0 - cxy;              // v_pk_add (neg)
            const f32x2 e1 = xy1 - cxy;
            const f32x2 q0 = e0 * e0;                // v_pk_mul
            const f32x2 q1 = e1 * e1;
            const f32x2 ez = pzp[j] - czz;           // 2 pts packed
            const f32x2 z2 = ez * ez;
            f32x2 dist;
            dist.x = (q0.x + q0.y) + z2.x;           // exact left-assoc, no contract
            dist.y = (q1.x + q1.y) + z2.y;
            dd[j] = __builtin_elementwise_min(dd[j], dist);
        }
        // best = max over 16 halves (max is exactly associative -> tree OK)
        f32x2 mp = dd[0];
#pragma unroll
        for (int j = 1; j < 8; ++j) mp = __builtin_elementwise_max(mp, dd[j]);
        float best = fmaxf(mp.x, mp.y);
        // smallest k with d[k]==best (== first-max semantics)
        int bk = 15;
#pragma unroll
        for (int k = 14; k >= 0; --k)
            if (dd[k >> 1][k & 1] == best) bk = k;
        const int bn = t * 16 + bk;

        // wave argmax: f32 max butterfly (all lanes get m), ballot for
        // lowest matching lane (= min n, since n is lex (lane,k) ordered)
        float m = best;
#pragma unroll
        for (int off = 32; off >= 1; off >>= 1)
            m = fmaxf(m, __shfl_xor(m, off));
        const unsigned long long eqm = __ballot(best == m);
        const int wl = (int)__builtin_ctzll(eqm);
        const int wn = __shfl(bn, wl);
        if (lane == 0)
            wkey[s & 1][wid] = (((unsigned long long)(~__float_as_uint(m))) << 14)
                             | (unsigned long long)(unsigned)wn;
        __syncthreads();
        // cross-wave: u64-min over 16 keys (max d, tie -> min n; wave n-ranges
        // ascend with wid so tie->min-wid == min n). Broadcast read + 4 levels.
        unsigned long long k2 = wkey[s & 1][lane & 15];
#pragma unroll
        for (int off = 8; off >= 1; off >>= 1) {
            const unsigned long long o = __shfl_xor(k2, off);
            if (o < k2) k2 = o;
        }
        far = (int)(k2 & 16383ull);
    }
}

// ---------------- Ball query: one 64-lane wave per centroid ----------------
// Selects the 32 smallest indices n with d2 < r^2 where
// d2 = (|s|^2 + |x|^2) - 2*(s.x)  (left-assoc f32, matching the reference).
// Fill short groups with the first valid index. Writes idx (as float) and grouped_xyz.
__global__ __launch_bounds__(256) void ballq_kernel(const float* __restrict__ xyz,
                                                    const float* __restrict__ radius_p,
                                                    float* out) {
    const int wib = threadIdx.x >> 6;
    const int lane = threadIdx.x & 63;
    const int gw = blockIdx.x * 4 + wib;   // 0..8191
    const int b = gw >> 10;
    const int s = gw & 1023;

    const float r = radius_p[0];
    const float r2 = __fmul_rn(r, r);

    const float* xb = xyz + (size_t)b * N * 3;
    const float* nx = out + OFF_NEWXYZ + (size_t)(b * NPOINT + s) * 3;
    const float c0 = nx[0], c1 = nx[1], c2 = nx[2];
    const float ss_s = __fadd_rn(__fadd_rn(__fmul_rn(c0, c0), __fmul_rn(c1, c1)),
                                 __fmul_rn(c2, c2));

    float* oidx = out + OFF_IDX + (size_t)(b * NPOINT + s) * NSAMPLE;
    float* ogx  = out + OFF_GXYZ + (size_t)(b * NPOINT + s) * NSAMPLE * 3;

    int filled = 0;
    int first = -1;
    for (int n0 = 0; n0 < N; n0 += 64) {
        const int n = n0 + lane;
        const float x = xb[n * 3 + 0];
        const float y = xb[n * 3 + 1];
        const float z = xb[n * 3 + 2];
        const float ssx = __fadd_rn(__fadd_rn(__fmul_rn(x, x), __fmul_rn(y, y)),
                                    __fmul_rn(z, z));
        const float dot = __fadd_rn(__fadd_rn(__fmul_rn(c0, x), __fmul_rn(c1, y)),
                                    __fmul_rn(c2, z));
        const float d2 = __fsub_rn(__fadd_rn(ss_s, ssx), __fmul_rn(2.0f, dot));
        const bool in = d2 < r2;
        const unsigned long long m = __ballot(in);
        if (first < 0 && m != 0ull) first = n0 + (int)__builtin_ctzll(m);
        if (in) {
            const int pos = filled + (int)__popcll(m & ((1ull << lane) - 1ull));
            if (pos < NSAMPLE) {
                oidx[pos] = (float)n;
                ogx[pos * 3 + 0] = __fsub_rn(x, c0);
                ogx[pos * 3 + 1] = __fsub_rn(y, c1);
                ogx[pos * 3 + 2] = __fsub_rn(z, c2);
            }
        }
        filled += (int)__popcll(m);
        if (filled >= NSAMPLE) break;
    }
    if (filled < NSAMPLE) {
        if (first < 0) first = 0;  // cannot happen (centroid is in its own ball), safety
        const float fx = xb[first * 3 + 0];
        const float fy = xb[first * 3 + 1];
        const float fz = xb[first * 3 + 2];
        const float g0 = __fsub_rn(fx, c0);
        const float g1 = __fsub_rn(fy, c1);
        const float g2 = __fsub_rn(fz, c2);
        for (int pos = filled + lane; pos < NSAMPLE; pos += 64) {
            oidx[pos] = (float)first;
            ogx[pos * 3 + 0] = g0;
            ogx[pos * 3 + 1] = g1;
            ogx[pos * 3 + 2] = g2;
        }
    }
}

// ---------------- new_points gather: one block per (b,s) ----------------
__global__ __launch_bounds__(256) void gather_kernel(const float* __restrict__ points,
                                                     float* out) {
    const int blk = blockIdx.x;            // b*NPOINT + s
    const int w = threadIdx.x >> 6;
    const int lane = threadIdx.x & 63;
    const int b = blk >> 10;

    const float* oidx = out + OFF_IDX + (size_t)blk * NSAMPLE;
    const float* pb = points + (size_t)b * N * CDIM;
    float* onp = out + OFF_NEWPTS + (size_t)blk * NSAMPLE * CDIM;

#pragma unroll
    for (int i = 0; i < 8; ++i) {
        const int slot = w * 8 + i;
        const int n = (int)oidx[slot];
        const float2 v = *(const float2*)(pb + (size_t)n * CDIM + lane * 2);
        *(float2*)(onp + (size_t)slot * CDIM + lane * 2) = v;
    }
}

extern "C" void kernel_launch(void* const* d_in, const int* in_sizes, int n_in,
                              void* d_out, int out_size, void* d_ws, size_t ws_size,
                              hipStream_t stream) {
    // inputs: [0]=npoint(int,1), [1]=radius(f32,1), [2]=xyz(f32, B*N*3), [3]=points(f32, B*N*CDIM)
    const float* xyz = (const float*)d_in[2];
    const float* points = (const float*)d_in[3];
    const float* radius = (const float*)d_in[1];
    float* out = (float*)d_out;

    hipLaunchKernelGGL(fps_kernel, dim3(B), dim3(1024), 0, stream, xyz, out);
    hipLaunchKernelGGL(ballq_kernel, dim3((B * NPOINT) / 4), dim3(256), 0, stream, xyz, radius, out);
    hipLaunchKernelGGL(gather_kernel, dim3(B * NPOINT), dim3(256), 0, stream, points, out);
}

// Round 11
// 1720.305 us; speedup vs baseline: 1.4377x; 1.1503x over previous
//
#include <hip/hip_runtime.h>

#define B 8
#define N 16384
#define NPOINT 1024
#define NSAMPLE 32
#define CDIM 128

// d_out layout (floats), reference return order:
// new_xyz [B,NPOINT,3], new_points [B,NPOINT,NSAMPLE,CDIM], idx [B,NPOINT,NSAMPLE], grouped_xyz [B,NPOINT,NSAMPLE,3]
#define OFF_NEWXYZ 0
#define OFF_NEWPTS (B * NPOINT * 3)                           // 24576
#define OFF_IDX    (OFF_NEWPTS + B * NPOINT * NSAMPLE * CDIM) // 33579008
#define OFF_GXYZ   (OFF_IDX + B * NPOINT * NSAMPLE)           // 33841152

typedef float f32x2 __attribute__((ext_vector_type(2)));

// DPP max step: m = max(m, lanes-shifted m). Invalid lanes keep old (=m) ->
// identity for max. Masks 0xf everywhere is safe (invalid => old).
template <int CTRL>
__device__ __forceinline__ float maxdpp(float m) {
    const int t = __builtin_amdgcn_update_dpp(__float_as_int(m), __float_as_int(m),
                                              CTRL, 0xf, 0xf, false);
    return fmaxf(m, __int_as_float(t));
}

// ---------------- FPS: one block (1024 threads) per batch ----------------
// Exact f32 left-assoc ops; fp-contract OFF. Thread t owns points
// [16t,16t+16); LDS slots transposed (point n=16t+k at slot k*1024+t) for
// conflict-free stride-8B ds_reads. Distance math packed (v_pk_*_f32).
// Argmax tail (the round-10 bottleneck) rebuilt for latency:
//   wave max   : DPP row_shr/row_bcast chain (VALU latency, no ds_swizzle)
//   block armax: single LDS atomicMin(u64 key), key = (~bits(d)<<14)|n —
//                min key == (max d, tie -> min n), the exact ref tie-break.
//   3-slot rotation keeps one barrier/step race-free:
//     epoch s: atomic into slot s%3; reset slot (s+1)%3 (its last readers
//     finished before barrier-(s-1)); barrier; read slot s%3.
__global__ __launch_bounds__(1024) void fps_kernel(const float* __restrict__ xyz,
                                                   float* out) {
#pragma clang fp contract(off)
    const int b = blockIdx.x;
    const int t = threadIdx.x;
    const float* xb = xyz + (size_t)b * N * 3;

    __shared__ float sxy[N * 2];              // (x,y) pairs, transposed slots — 128 KiB
    __shared__ unsigned long long wloc[3];    // rotating argmax cells

    f32x2 pzp[8], dd[8];
#pragma unroll
    for (int k = 0; k < 16; ++k) {
        const int n = t * 16 + k;            // thread-contiguous point ownership
        const int slot = k * 1024 + t;       // transposed LDS slot
        sxy[slot * 2 + 0] = xb[n * 3 + 0];
        sxy[slot * 2 + 1] = xb[n * 3 + 1];
        pzp[k >> 1][k & 1] = xb[n * 3 + 2];
        dd[k >> 1][k & 1] = 1e10f;
    }
    if (t < 3) wloc[t] = ~0ull;
    __syncthreads();

    float* nxo = out + OFF_NEWXYZ + (size_t)b * NPOINT * 3;
    int far = 0;
    int cur = 0;

    for (int s = 0; s < NPOINT; ++s) {
        // centroid: (x,y) via uniform LDS broadcast read; z via uniform s_load.
        const int fs = __builtin_amdgcn_readfirstlane(far);
        const int fslot = (fs & 15) * 1024 + (fs >> 4);
        const f32x2 cl = *(const f32x2*)(&sxy[fslot * 2]);
        const float cz = xb[fs * 3 + 2];
        const float cx = cl.x, cy = cl.y;
        if (t == 0) {
            nxo[s * 3 + 0] = cx;
            nxo[s * 3 + 1] = cy;
            nxo[s * 3 + 2] = cz;
        }
        if (s == NPOINT - 1) break;                  // last argmax is discarded

        const f32x2 cxy = {cx, cy};
        const f32x2 czz = {cz, cz};
#pragma unroll
        for (int j = 0; j < 8; ++j) {                // 2 points per iter, packed
            const int slot0 = (2 * j) * 1024 + t;
            const int slot1 = (2 * j + 1) * 1024 + t;
            const f32x2 xy0 = *(const f32x2*)(&sxy[slot0 * 2]);  // ds_read_b64
            const f32x2 xy1 = *(const f32x2*)(&sxy[slot1 * 2]);
            const f32x2 e0 = xy0 - cxy;              // v_pk_add (neg)
            const f32x2 e1 = xy1 - cxy;
            const f32x2 q0 = e0 * e0;                // v_pk_mul
            const f32x2 q1 = e1 * e1;
            const f32x2 ez = pzp[j] - czz;           // 2 pts packed
            const f32x2 z2 = ez * ez;
            f32x2 dist;
            dist.x = (q0.x + q0.y) + z2.x;           // exact left-assoc, no contract
            dist.y = (q1.x + q1.y) + z2.y;
            dd[j] = __builtin_elementwise_min(dd[j], dist);
        }
        // best = max over 16 halves (max is exactly associative -> tree OK)
        f32x2 mp = dd[0];
#pragma unroll
        for (int j = 1; j < 8; ++j) mp = __builtin_elementwise_max(mp, dd[j]);
        float best = fmaxf(mp.x, mp.y);
        // smallest k with d[k]==best (== first-max semantics)
        int bk = 15;
#pragma unroll
        for (int k = 14; k >= 0; --k)
            if (dd[k >> 1][k & 1] == best) bk = k;
        const int bn = t * 16 + bk;

        // wave max via DPP (VALU-latency chain, lane 63 ends with wave max)
        float m = best;
        m = maxdpp<0x111>(m);   // row_shr:1
        m = maxdpp<0x112>(m);   // row_shr:2
        m = maxdpp<0x114>(m);   // row_shr:4
        m = maxdpp<0x118>(m);   // row_shr:8
        m = maxdpp<0x142>(m);   // row_bcast:15
        m = maxdpp<0x143>(m);   // row_bcast:31
        const float wavemax =
            __int_as_float(__builtin_amdgcn_readlane(__float_as_int(m), 63));

        // block argmax: candidates (>=1 per wave) atomic-min their packed key.
        // d >= 0 always, so ~bits(d) is monotone decreasing -> u64-min is
        // (max d, tie -> min n) exactly.
        if (best == wavemax) {
            const unsigned long long key =
                (((unsigned long long)(~__float_as_uint(best))) << 14) |
                (unsigned long long)(unsigned)bn;
            atomicMin(&wloc[cur], key);
        }
        if (t == 0) wloc[cur == 2 ? 0 : cur + 1] = ~0ull;  // prep step s+1's cell
        __syncthreads();
        far = (int)(wloc[cur] & 16383ull);
        cur = (cur == 2) ? 0 : cur + 1;
    }
}

// ---------------- Ball query: one 64-lane wave per centroid ----------------
// Selects the 32 smallest indices n with d2 < r^2 where
// d2 = (|s|^2 + |x|^2) - 2*(s.x)  (left-assoc f32, matching the reference).
// Fill short groups with the first valid index. Writes idx (as float) and grouped_xyz.
__global__ __launch_bounds__(256) void ballq_kernel(const float* __restrict__ xyz,
                                                    const float* __restrict__ radius_p,
                                                    float* out) {
    const int wib = threadIdx.x >> 6;
    const int lane = threadIdx.x & 63;
    const int gw = blockIdx.x * 4 + wib;   // 0..8191
    const int b = gw >> 10;
    const int s = gw & 1023;

    const float r = radius_p[0];
    const float r2 = __fmul_rn(r, r);

    const float* xb = xyz + (size_t)b * N * 3;
    const float* nx = out + OFF_NEWXYZ + (size_t)(b * NPOINT + s) * 3;
    const float c0 = nx[0], c1 = nx[1], c2 = nx[2];
    const float ss_s = __fadd_rn(__fadd_rn(__fmul_rn(c0, c0), __fmul_rn(c1, c1)),
                                 __fmul_rn(c2, c2));

    float* oidx = out + OFF_IDX + (size_t)(b * NPOINT + s) * NSAMPLE;
    float* ogx  = out + OFF_GXYZ + (size_t)(b * NPOINT + s) * NSAMPLE * 3;

    int filled = 0;
    int first = -1;
    for (int n0 = 0; n0 < N; n0 += 64) {
        const int n = n0 + lane;
        const float x = xb[n * 3 + 0];
        const float y = xb[n * 3 + 1];
        const float z = xb[n * 3 + 2];
        const float ssx = __fadd_rn(__fadd_rn(__fmul_rn(x, x), __fmul_rn(y, y)),
                                    __fmul_rn(z, z));
        const float dot = __fadd_rn(__fadd_rn(__fmul_rn(c0, x), __fmul_rn(c1, y)),
                                    __fmul_rn(c2, z));
        const float d2 = __fsub_rn(__fadd_rn(ss_s, ssx), __fmul_rn(2.0f, dot));
        const bool in = d2 < r2;
        const unsigned long long m = __ballot(in);
        if (first < 0 && m != 0ull) first = n0 + (int)__builtin_ctzll(m);
        if (in) {
            const int pos = filled + (int)__popcll(m & ((1ull << lane) - 1ull));
            if (pos < NSAMPLE) {
                oidx[pos] = (float)n;
                ogx[pos * 3 + 0] = __fsub_rn(x, c0);
                ogx[pos * 3 + 1] = __fsub_rn(y, c1);
                ogx[pos * 3 + 2] = __fsub_rn(z, c2);
            }
        }
        filled += (int)__popcll(m);
        if (filled >= NSAMPLE) break;
    }
    if (filled < NSAMPLE) {
        if (first < 0) first = 0;  // cannot happen (centroid is in its own ball), safety
        const float fx = xb[first * 3 + 0];
        const float fy = xb[first * 3 + 1];
        const float fz = xb[first * 3 + 2];
        const float g0 = __fsub_rn(fx, c0);
        const float g1 = __fsub_rn(fy, c1);
        const float g2 = __fsub_rn(fz, c2);
        for (int pos = filled + lane; pos < NSAMPLE; pos += 64) {
            oidx[pos] = (float)first;
            ogx[pos * 3 + 0] = g0;
            ogx[pos * 3 + 1] = g1;
            ogx[pos * 3 + 2] = g2;
        }
    }
}

// ---------------- new_points gather: one block per (b,s) ----------------
__global__ __launch_bounds__(256) void gather_kernel(const float* __restrict__ points,
                                                     float* out) {
    const int blk = blockIdx.x;            // b*NPOINT + s
    const int w = threadIdx.x >> 6;
    const int lane = threadIdx.x & 63;
    const int b = blk >> 10;

    const float* oidx = out + OFF_IDX + (size_t)blk * NSAMPLE;
    const float* pb = points + (size_t)b * N * CDIM;
    float* onp = out + OFF_NEWPTS + (size_t)blk * NSAMPLE * CDIM;

#pragma unroll
    for (int i = 0; i < 8; ++i) {
        const int slot = w * 8 + i;
        const int n = (int)oidx[slot];
        const float2 v = *(const float2*)(pb + (size_t)n * CDIM + lane * 2);
        *(float2*)(onp + (size_t)slot * CDIM + lane * 2) = v;
    }
}

extern "C" void kernel_launch(void* const* d_in, const int* in_sizes, int n_in,
                              void* d_out, int out_size, void* d_ws, size_t ws_size,
                              hipStream_t stream) {
    // inputs: [0]=npoint(int,1), [1]=radius(f32,1), [2]=xyz(f32, B*N*3), [3]=points(f32, B*N*CDIM)
    const float* xyz = (const float*)d_in[2];
    const float* points = (const float*)d_in[3];
    const float* radius = (const float*)d_in[1];
    float* out = (float*)d_out;

    hipLaunchKernelGGL(fps_kernel, dim3(B), dim3(1024), 0, stream, xyz, out);
    hipLaunchKernelGGL(ballq_kernel, dim3((B * NPOINT) / 4), dim3(256), 0, stream, xyz, radius, out);
    hipLaunchKernelGGL(gather_kernel, dim3(B * NPOINT), dim3(256), 0, stream, points, out);
}